// Round 7
// baseline (209.425 us; speedup 1.0000x reference)
//
#include <hip/hip_runtime.h>
#include <hip/hip_bf16.h>

#define SLEN   2048
#define DMODEL 1024
#define NHEADS 16
#define DHEAD  64
#define NBATCH 2
#define EPAD_ROWS 2432   // SLEN + 384 zero rows so rel-band never reads OOB

// Q pre-scale folds softmax 1/8 AND log2(e) so scores are in exp2 domain
#define QSCALE 0.18033688011112042f     // 0.125 * log2(e)
#define EXPB   23.083120654223414f      // 16 * log2(e)

typedef __bf16 bf16x8 __attribute__((ext_vector_type(8)));
typedef float  f32x4  __attribute__((ext_vector_type(4)));

__device__ __forceinline__ unsigned short f2bf(float f) {
    unsigned int u = __builtin_bit_cast(unsigned int, f);
    return (unsigned short)((u + 0x7fffu + ((u >> 16) & 1u)) >> 16);  // RNE
}

// bare v_exp_f32 (2^x); args in [-60, 20], flush-to-zero fine
__device__ __forceinline__ float exp2_hw(float x) {
    float r;
    asm("v_exp_f32 %0, %1" : "=v"(r) : "v"(x));
    return r;
}

// pack two f32 -> (bf16 lo, bf16 hi), RNE
__device__ __forceinline__ unsigned int cvtpk_bf16(float lo, float hi) {
    unsigned int d;
    asm("v_cvt_pk_bf16_f32 %0, %1, %2" : "=v"(d) : "v"(lo), "v"(hi));
    return d;
}

__device__ __forceinline__ bf16x8 ld8(const unsigned short* p) {
    union { uint4 u; bf16x8 b; } t;
    t.u = *(const uint4*)p;
    return t.b;
}

__device__ __forceinline__ bf16x8 u2b(uint4 u) {
    union { uint4 u; bf16x8 b; } t;
    t.u = u;
    return t.b;
}

// inline-asm global load: pinned issue point (compiler cannot sink it)
#define LDG16(dst, ptr, offbytes)                                        \
    asm volatile("global_load_dwordx4 %0, %1, off offset:" #offbytes     \
                 : "=v"(dst) : "v"(ptr))

// async global->LDS, 16B per lane; lds base must be wave-uniform
__device__ __forceinline__ void glds16(const unsigned short* g, unsigned short* l) {
    __builtin_amdgcn_global_load_lds(
        (const __attribute__((address_space(1))) unsigned int*)g,
        (__attribute__((address_space(3))) unsigned int*)l, 16, 0, 0);
}

// ---------------- merged prep kernel ----------------
__global__ __launch_bounds__(256) void prep_kernel(
    const float* __restrict__ x, const float* __restrict__ Er,
    const float* __restrict__ Wq, const float* __restrict__ Wk,
    const float* __restrict__ Wv,
    unsigned short* __restrict__ xb, unsigned short* __restrict__ Ep,
    unsigned short* __restrict__ Wt) {
    const int bi = blockIdx.x, tid = threadIdx.x;
    if (bi < 4096) {
        int i = (bi * 256 + tid) * 4;
        float4 v = *(const float4*)(x + i);
        ushort4 o;
        o.x = f2bf(v.x); o.y = f2bf(v.y); o.z = f2bf(v.z); o.w = f2bf(v.w);
        *(ushort4*)(xb + i) = o;
    } else if (bi < 4704) {
        int i = (bi - 4096) * 256 + tid;        // 2432*64 elements
        int row = i >> 6;
        unsigned short v = 0;
        if (row < SLEN) v = f2bf(Er[i]);
        Ep[i] = v;
    } else {
        __shared__ float tile[32][33];
        const int b3 = bi - 4704;               // 0..3071
        const int z = b3 >> 10, rem = b3 & 1023;
        const int n0 = (rem & 31) * 32, k0 = (rem >> 5) * 32;
        const float* W = (z == 0) ? Wq : (z == 1 ? Wk : Wv);
        unsigned short* out = Wt + (size_t)z * DMODEL * DMODEL;
        const int tx = tid & 31, ty = tid >> 5;  // (32,8)
        for (int r = 0; r < 32; r += 8)
            tile[ty + r][tx] = W[(size_t)(k0 + ty + r) * DMODEL + n0 + tx];
        __syncthreads();
        for (int r = 0; r < 32; r += 8)
            out[(size_t)(n0 + ty + r) * DMODEL + k0 + tx] = f2bf(tile[tx][ty + r]);
    }
}

// ---------------- QKV projection GEMM (R3 config, unchanged) ----------------
__global__ __launch_bounds__(256, 3) void qkv_gemm(
    const unsigned short* __restrict__ xb, const unsigned short* __restrict__ Wt,
    const float* __restrict__ bq, const float* __restrict__ bk, const float* __restrict__ bv,
    unsigned short* __restrict__ Qs, unsigned short* __restrict__ Ks,
    unsigned short* __restrict__ Vts) {
    const int b = blockIdx.x;
    const int x7 = b & 7, s = b >> 3;
    const int mt = ((x7 >> 1) << 3) | (s & 7);          // 0..31
    const int ntile = ((x7 & 1) << 2) | ((s >> 3) & 3); // 0..7
    const int z = s >> 5;                               // 0..2
    const int m0 = mt * 128, n0 = ntile * 128;

    const float* bias = (z == 0) ? bq : (z == 1 ? bk : bv);
    const unsigned short* Wz = Wt + (size_t)z * DMODEL * DMODEL;

    __shared__ __align__(16) unsigned short As[128][64];
    __shared__ __align__(16) unsigned short Bs[128][64];

    const int tid = threadIdx.x;
    const int wave = tid >> 6, lane = tid & 63, l16 = lane & 15, quad = lane >> 4;
    const int wm = (wave >> 1) * 64, wn = (wave & 1) * 64;

    const int lr8 = lane >> 3;
    const int sc  = ((lane & 7) ^ lr8) * 8;    // swizzled source col (u16)

    f32x4 acc[4][4];
#pragma unroll
    for (int mi = 0; mi < 4; mi++)
#pragma unroll
        for (int ni = 0; ni < 4; ni++) acc[mi][ni] = (f32x4){0.f, 0.f, 0.f, 0.f};

    for (int j = 0; j < 16; ++j) {
        if (j) __syncthreads();                // readers of tile j-1 done
        const int k0 = j * 64;
#pragma unroll
        for (int c = 0; c < 4; c++) {
            const int seg = wave * 4 + c;
            const int r8  = seg * 8 + lr8;
            glds16(&xb[(size_t)(m0 + r8) * DMODEL + k0 + sc], &As[seg * 8][0]);
            glds16(&Wz[(size_t)(n0 + r8) * DMODEL + k0 + sc], &Bs[seg * 8][0]);
        }
        __syncthreads();                       // stage landed (vmcnt drained)

        const unsigned short (*Aarr)[64] = (z == 2) ? Bs : As;
        const unsigned short (*Barr)[64] = (z == 2) ? As : Bs;
#pragma unroll
        for (int ks = 0; ks < 2; ks++) {
            const int pc = ((ks * 4 + quad) ^ (l16 & 7)) * 8;
            bf16x8 a[4], bb[4];
#pragma unroll
            for (int mi = 0; mi < 4; mi++) a[mi] = ld8(&Aarr[wm + mi * 16 + l16][pc]);
#pragma unroll
            for (int ni = 0; ni < 4; ni++) bb[ni] = ld8(&Barr[wn + ni * 16 + l16][pc]);
#pragma unroll
            for (int mi = 0; mi < 4; mi++)
#pragma unroll
                for (int ni = 0; ni < 4; ni++)
                    acc[mi][ni] = __builtin_amdgcn_mfma_f32_16x16x32_bf16(a[mi], bb[ni], acc[mi][ni], 0, 0, 0);
        }
    }

    if (z == 2) {
#pragma unroll
        for (int mi = 0; mi < 4; mi++)
#pragma unroll
            for (int r = 0; r < 4; r++) {
                const int n = n0 + wm + mi * 16 + quad * 4 + r;
                const float bb = bias[n];
                const int h = n >> 6, d = n & 63;
#pragma unroll
                for (int ni = 0; ni < 4; ni++) {
                    const int m = m0 + wn + ni * 16 + l16;
                    const int bi = m >> 11, ss = m & 2047;
                    Vts[((size_t)((bi * NHEADS + h) * 64 + d)) * SLEN + ss] = f2bf(acc[mi][ni][r] + bb);
                }
            }
    } else {
#pragma unroll
        for (int ni = 0; ni < 4; ni++) {
            const int n = n0 + wn + ni * 16 + l16;
            const float bb = bias[n];
            const int h = n >> 6, d = n & 63;
#pragma unroll
            for (int mi = 0; mi < 4; mi++)
#pragma unroll
                for (int r = 0; r < 4; r++) {
                    const int m = m0 + wm + mi * 16 + quad * 4 + r;
                    const int bi = m >> 11, ss = m & 2047;
                    float v = acc[mi][ni][r] + bb;
                    if (z == 0)
                        Qs[((size_t)(bi * NHEADS + h) * SLEN + ss) * 64 + d] = f2bf(v * QSCALE);
                    else
                        Ks[((size_t)(bi * NHEADS + h) * SLEN + ss) * 64 + d] = f2bf(v);
                }
        }
    }
}

// ---------------- cooperative flash attention — R7 ---------------------------
// R6 swapped-operand structure + Er band moved from LDS ring to REGISTERS via
// pinned inline-asm global loads (L2-resident, 311 KB). Issue order per iter:
// [10x LDG Er(j)] -> [4x glds16 K/V(j+1), unconditional] -> QK -> vmcnt(4)+
// sched_barrier -> E-MFMA(reg frags). vmcnt retires in issue order, so
// vmcnt(4) == all Er done, staging still in flight. Esh deleted: LDS 64->32KB
// -> 3 blocks/CU (launch_bounds(256,3), VGPR cap 170). This fixes R1's
// failure (compiler sank plain loads to use -> exposed L2 latency @ 2 waves).
__global__ __launch_bounds__(256, 3) void attn_kernel(
    const unsigned short* __restrict__ Q,   // (BH,S,64), pre-scaled by QSCALE
    const unsigned short* __restrict__ K,   // (BH,S,64)
    const unsigned short* __restrict__ Vt,  // (BH,64,S)
    const unsigned short* __restrict__ Ep,  // (EPAD_ROWS,64) bf16, zero-padded
    float* __restrict__ out) {              // (B,S,DMODEL)
    const int tid = threadIdx.x;
    const int wave = tid >> 6, lane = tid & 63, l16 = lane & 15, quad = lane >> 4;
    const int lr8 = lane >> 3;
    const int swz = ((lane & 7) ^ lr8) * 8;   // swizzled source chunk (u16)

    const int bh = blockIdx.x & 31;
    const int pg = blockIdx.x >> 5;            // 0..15

    __shared__ __align__(16) unsigned short Ksh[2][64 * 64];  // K tile  [t][d], dbuf
    __shared__ __align__(16) unsigned short Vsh[2][64 * 64];  // V^T tile[d][t], dbuf

    const unsigned short* Qb = Q + (size_t)bh * SLEN * 64;
    const unsigned short* Kb = K + (size_t)bh * SLEN * 64;
    const unsigned short* Vb = Vt + (size_t)bh * 64 * SLEN;
    const int ob = bh >> 4, oh = bh & 15;

    // hoisted loop-invariant lane math
    const int pc0 = (quad ^ (l16 & 7)) * 8;          // de-swizzle, k-chunk 0
    const int pc1 = ((4 + quad) ^ (l16 & 7)) * 8;    // de-swizzle, k-chunk 1
    // skew gather (swapped layout): receiver (quad,l16) output (nt,r) needs
    // band offset o = nt*16 + idx_v, idx_v = quad*4 + r + 15 - l16, served by
    // lane ((idx_v&15)>>2, l16) register (nt + (idx_v>=16))[idx_v&3].
    const int krot = (15 - l16) & 3;
    const bool c1 = (krot & 1) != 0, c2 = (krot & 2) != 0;
    int permE[4]; bool hiE[4];
#pragma unroll
    for (int r = 0; r < 4; r++) {
        const int idx = quad * 4 + r + 15 - l16;     // receiver-side idx_v: 0..30
        permE[r] = ((idx >> 2) & 3) * 16 + l16;      // sender lane to pull from
        const int c  = r + 15 - l16;                 // sender-side: 0..18
        const int qv = (quad - (c >> 2)) & 3;        // quad of receiver I serve
        hiE[r] = (qv * 4 + c) >= 16;                 // that receiver's idx_v>=16
    }

    // per-lane invariant byte offset within an Er row-group: row +l16, col quad*8
    const unsigned short* ep_lane = Ep + (size_t)l16 * 64 + quad * 8;

    int s0 = pg * 64;
    int ntp = pg + 1;

#pragma unroll 1
    for (int pass = 0; pass < 2; ++pass) {
        const int sw = s0 + 16 * wave;          // this wave's 16 q-rows
        const bf16x8 aq0 = ld8(Qb + (size_t)(sw + l16) * 64 + quad * 8);
        const bf16x8 aq1 = ld8(Qb + (size_t)(sw + l16) * 64 + 32 + quad * 8);

        f32x4 accO[4];                          // O^T: d = ntd*16+quad*4+r, q=l16
        float sacc[4];
#pragma unroll
        for (int nt = 0; nt < 4; nt++) accO[nt] = (f32x4){0.f, 0.f, 0.f, 0.f};
#pragma unroll
        for (int r = 0; r < 4; r++) sacc[r] = 0.f;

        // Er band base for this wave at t0=0: rows SLEN-16-sw .. +79
        const unsigned short* eb0 = ep_lane + (size_t)(SLEN - 16 - sw) * 64;

        // ---- prologue: K/V (t0=0) into buf0 ----
#pragma unroll
        for (int c = 0; c < 2; c++) {
            const int seg = wave * 2 + c;
            glds16(&Kb[(size_t)(seg * 8 + lr8) * 64 + swz], &Ksh[0][seg * 8 * 64]);
            glds16(&Vb[(size_t)(seg * 8 + lr8) * SLEN + swz], &Vsh[0][seg * 8 * 64]);
        }
        __syncthreads();

        for (int j = 0; j < ntp; ++j) {
            const int t0 = j * 64;
            const int cur = j & 1;

            // ---- 1) pinned Er loads for THIS iter (10x b128, VMEM pipe) ----
            // group nt: +nt*16 rows = +nt*2048 B; k-chunk 1: +32 u16 = +64 B
            const unsigned short* e0 = eb0 + (size_t)t0 * 64;      // nt 0,1
            const unsigned short* e1 = e0 + 2048;                   // nt 2,3 (+4096B)
            const unsigned short* e2 = e0 + 4096;                   // nt 4   (+8192B)
            uint4 eb[5][2];
            LDG16(eb[0][0], e0, 0);    LDG16(eb[0][1], e0, 64);
            LDG16(eb[1][0], e0, 2048); LDG16(eb[1][1], e0, 2112);
            LDG16(eb[2][0], e1, 0);    LDG16(eb[2][1], e1, 64);
            LDG16(eb[3][0], e1, 2048); LDG16(eb[3][1], e1, 2112);
            LDG16(eb[4][0], e2, 0);    LDG16(eb[4][1], e2, 64);

            // ---- 2) stage next K/V tile (unconditional: keeps vmcnt(4)
            //         invariant on the last iter; tail reads land in allocated
            //         workspace and are never consumed) ----
            {
                const int t1 = t0 + 64, nb = cur ^ 1;
#pragma unroll
                for (int c = 0; c < 2; c++) {
                    const int seg = wave * 2 + c;
                    glds16(&Kb[(size_t)(t1 + seg * 8 + lr8) * 64 + swz], &Ksh[nb][seg * 8 * 64]);
                    glds16(&Vb[(size_t)(seg * 8 + lr8) * SLEN + t1 + swz], &Vsh[nb][seg * 8 * 64]);
                }
            }

            // ---- 3) QK^T swapped: S^T[t][q], t = nt*16+quad*4+r, q = l16 ----
            f32x4 accS[4];
#pragma unroll
            for (int nt = 0; nt < 4; nt++)
                accS[nt] = (f32x4){-EXPB, -EXPB, -EXPB, -EXPB};
#pragma unroll
            for (int nt = 0; nt < 4; nt++) {
                bf16x8 bk0 = ld8(&Ksh[cur][(nt * 16 + l16) * 64 + pc0]);
                bf16x8 bk1 = ld8(&Ksh[cur][(nt * 16 + l16) * 64 + pc1]);
                accS[nt] = __builtin_amdgcn_mfma_f32_16x16x32_bf16(bk0, aq0, accS[nt], 0, 0, 0);
                accS[nt] = __builtin_amdgcn_mfma_f32_16x16x32_bf16(bk1, aq1, accS[nt], 0, 0, 0);
            }

            // ---- 4) gate: all 10 Er loads retired (4 staging may fly) ----
            asm volatile("s_waitcnt vmcnt(4)" ::: "memory");
            __builtin_amdgcn_sched_barrier(0);

            // ---- 5) rel band from register frags: E^T[band row][q] ----
            f32x4 accE[5];
#pragma unroll
            for (int nt = 0; nt < 5; nt++) accE[nt] = (f32x4){0.f, 0.f, 0.f, 0.f};
#pragma unroll
            for (int nt = 0; nt < 5; nt++) {
                accE[nt] = __builtin_amdgcn_mfma_f32_16x16x32_bf16(u2b(eb[nt][0]), aq0, accE[nt], 0, 0, 0);
                accE[nt] = __builtin_amdgcn_mfma_f32_16x16x32_bf16(u2b(eb[nt][1]), aq1, accE[nt], 0, 0, 0);
            }

            // ---- per-lane register rotation of accE groups by krot ----
            f32x4 rotE[5];
#pragma unroll
            for (int g = 0; g < 5; g++) {
                f32x4 A = accE[g], t, rt;
#pragma unroll
                for (int r = 0; r < 4; r++) t[r] = c1 ? A[(r + 1) & 3] : A[r];
#pragma unroll
                for (int r = 0; r < 4; r++) rt[r] = c2 ? t[(r + 2) & 3] : t[r];
                rotE[g] = rt;
            }

            // ---- skew gather + exp2 (mask only on diagonal tile) ----
            float pe[4][4];
            auto scoreblk = [&](bool masked) {
#pragma unroll
                for (int nt = 0; nt < 4; nt++) {
#pragma unroll
                    for (int r = 0; r < 4; r++) {
                        float send = hiE[r] ? rotE[nt + 1][r] : rotE[nt][r];
                        float rel = __shfl(send, permE[r]);
                        float p = exp2_hw(accS[nt][r] + rel);
                        if (masked)
                            p = (t0 + nt * 16 + quad * 4 + r <= sw + l16) ? p : 0.0f;
                        sacc[r] += p;
                        pe[nt][r] = p;
                    }
                }
            };
            if (t0 + 63 <= sw) scoreblk(false);   // fully-unmasked tile
            else               scoreblk(true);    // diagonal tile

            // ---- P^T -> bf16 B-frags, in-register (cvt_pk + permlane) ----
            unsigned int w[4][2];
#pragma unroll
            for (int nt = 0; nt < 4; nt++) {
                w[nt][0] = cvtpk_bf16(pe[nt][0], pe[nt][1]);
                w[nt][1] = cvtpk_bf16(pe[nt][2], pe[nt][3]);
            }
            bf16x8 pf[2];
#pragma unroll
            for (int c = 0; c < 2; c++) {
                unsigned int a0 = w[2 * c][0], b0 = w[2 * c + 1][0];
                unsigned int a1 = w[2 * c][1], b1 = w[2 * c + 1][1];
                asm volatile("v_permlane32_swap_b32 %0, %1" : "+v"(a0), "+v"(b0));
                asm volatile("v_permlane16_swap_b32 %0, %1" : "+v"(a0), "+v"(b0));
                asm volatile("v_permlane32_swap_b32 %0, %1" : "+v"(a1), "+v"(b1));
                asm volatile("v_permlane16_swap_b32 %0, %1" : "+v"(a1), "+v"(b1));
                union { uint4 u; bf16x8 b; } t;
                t.u = (uint4){a0, a1, b0, b1};
                pf[c] = t.b;
            }

            // ---- PV swapped: O^T += V^T x P^T ----
#pragma unroll
            for (int ntd = 0; ntd < 4; ntd++) {
                bf16x8 bv0 = ld8(&Vsh[cur][(ntd * 16 + l16) * 64 + pc0]);
                bf16x8 bv1 = ld8(&Vsh[cur][(ntd * 16 + l16) * 64 + pc1]);
                accO[ntd] = __builtin_amdgcn_mfma_f32_16x16x32_bf16(bv0, pf[0], accO[ntd], 0, 0, 0);
                accO[ntd] = __builtin_amdgcn_mfma_f32_16x16x32_bf16(bv1, pf[1], accO[ntd], 0, 0, 0);
            }

            __syncthreads();   // staged j+1 landed; compute j done before overwrite
        }

        // ---- pass epilogue: cross-quad denom reduce + normalize + store ----
        float s4 = (sacc[0] + sacc[1]) + (sacc[2] + sacc[3]);
        s4 += __shfl_xor(s4, 16);
        s4 += __shfl_xor(s4, 32);
        const float inv = 1.f / s4;
        const int srow = sw + l16;
        float* orow = out + ((size_t)(ob * SLEN + srow)) * DMODEL + oh * 64 + quad * 4;
#pragma unroll
        for (int ntd = 0; ntd < 4; ntd++) {
            float4 st = {accO[ntd][0] * inv, accO[ntd][1] * inv,
                         accO[ntd][2] * inv, accO[ntd][3] * inv};
            *(float4*)(orow + ntd * 16) = st;
        }

        // switch to pass B: q-tile 31-pg
        s0 = (31 - pg) * 64;
        ntp = 32 - pg;
    }
}

// ---------------- host launcher ----------------
extern "C" void kernel_launch(void* const* d_in, const int* in_sizes, int n_in,
                              void* d_out, int out_size, void* d_ws, size_t ws_size,
                              hipStream_t stream) {
    const float* x  = (const float*)d_in[0];
    const float* Wq = (const float*)d_in[1];
    const float* bq = (const float*)d_in[2];
    const float* Wk = (const float*)d_in[3];
    const float* bk = (const float*)d_in[4];
    const float* Wv = (const float*)d_in[5];
    const float* bv = (const float*)d_in[6];
    const float* Er = (const float*)d_in[7];
    float* out = (float*)d_out;

    // workspace carve (~38.4 MB total)
    char* p = (char*)d_ws;
    unsigned short* xb  = (unsigned short*)p; p += (size_t)4096 * 1024 * 2;
    unsigned short* Wt  = (unsigned short*)p; p += (size_t)3 * 1024 * 1024 * 2;
    unsigned short* Qs  = (unsigned short*)p; p += (size_t)32 * 2048 * 64 * 2;
    unsigned short* Ks  = (unsigned short*)p; p += (size_t)32 * 2048 * 64 * 2;
    unsigned short* Vts = (unsigned short*)p; p += (size_t)32 * 2048 * 64 * 2;
    unsigned short* Ep  = (unsigned short*)p; p += (size_t)EPAD_ROWS * 64 * 2;

    hipLaunchKernelGGL(prep_kernel, dim3(7776), dim3(256), 0, stream,
                       x, Er, Wq, Wk, Wv, xb, Ep, Wt);
    hipLaunchKernelGGL(qkv_gemm, dim3(768), dim3(256), 0, stream,
                       xb, Wt, bq, bk, bv, Qs, Ks, Vts);
    hipLaunchKernelGGL(attn_kernel, dim3(512), dim3(256), 0, stream, Qs, Ks, Vts, Ep, out);
}

// Round 8
// 171.092 us; speedup vs baseline: 1.2240x; 1.2240x over previous
//
#include <hip/hip_runtime.h>
#include <hip/hip_bf16.h>

#define SLEN   2048
#define DMODEL 1024
#define NHEADS 16
#define DHEAD  64
#define NBATCH 2
#define EPAD_ROWS 2432   // SLEN + 384 zero rows so rel-band/ring never reads OOB

// Q pre-scale folds softmax 1/8 AND log2(e) so scores are in exp2 domain
#define QSCALE 0.18033688011112042f     // 0.125 * log2(e)
#define EXPB   23.083120654223414f      // 16 * log2(e)

typedef __bf16 bf16x8 __attribute__((ext_vector_type(8)));
typedef float  f32x4  __attribute__((ext_vector_type(4)));

__device__ __forceinline__ unsigned short f2bf(float f) {
    unsigned int u = __builtin_bit_cast(unsigned int, f);
    return (unsigned short)((u + 0x7fffu + ((u >> 16) & 1u)) >> 16);  // RNE
}

// bare v_exp_f32 (2^x); args in [-60, 20], flush-to-zero fine
__device__ __forceinline__ float exp2_hw(float x) {
    float r;
    asm("v_exp_f32 %0, %1" : "=v"(r) : "v"(x));
    return r;
}

// pack two f32 -> (bf16 lo, bf16 hi), RNE
__device__ __forceinline__ unsigned int cvtpk_bf16(float lo, float hi) {
    unsigned int d;
    asm("v_cvt_pk_bf16_f32 %0, %1, %2" : "=v"(d) : "v"(lo), "v"(hi));
    return d;
}

__device__ __forceinline__ bf16x8 ld8(const unsigned short* p) {
    union { uint4 u; bf16x8 b; } t;
    t.u = *(const uint4*)p;
    return t.b;
}

// async global->LDS, 16B per lane; lds base must be wave-uniform
__device__ __forceinline__ void glds16(const unsigned short* g, unsigned short* l) {
    __builtin_amdgcn_global_load_lds(
        (const __attribute__((address_space(1))) unsigned int*)g,
        (__attribute__((address_space(3))) unsigned int*)l, 16, 0, 0);
}

// ---------------- merged prep kernel ----------------
__global__ __launch_bounds__(256) void prep_kernel(
    const float* __restrict__ x, const float* __restrict__ Er,
    const float* __restrict__ Wq, const float* __restrict__ Wk,
    const float* __restrict__ Wv,
    unsigned short* __restrict__ xb, unsigned short* __restrict__ Ep,
    unsigned short* __restrict__ Wt) {
    const int bi = blockIdx.x, tid = threadIdx.x;
    if (bi < 4096) {
        int i = (bi * 256 + tid) * 4;
        float4 v = *(const float4*)(x + i);
        ushort4 o;
        o.x = f2bf(v.x); o.y = f2bf(v.y); o.z = f2bf(v.z); o.w = f2bf(v.w);
        *(ushort4*)(xb + i) = o;
    } else if (bi < 4704) {
        int i = (bi - 4096) * 256 + tid;        // 2432*64 elements
        int row = i >> 6;
        unsigned short v = 0;
        if (row < SLEN) v = f2bf(Er[i]);
        Ep[i] = v;
    } else {
        __shared__ float tile[32][33];
        const int b3 = bi - 4704;               // 0..3071
        const int z = b3 >> 10, rem = b3 & 1023;
        const int n0 = (rem & 31) * 32, k0 = (rem >> 5) * 32;
        const float* W = (z == 0) ? Wq : (z == 1 ? Wk : Wv);
        unsigned short* out = Wt + (size_t)z * DMODEL * DMODEL;
        const int tx = tid & 31, ty = tid >> 5;  // (32,8)
        for (int r = 0; r < 32; r += 8)
            tile[ty + r][tx] = W[(size_t)(k0 + ty + r) * DMODEL + n0 + tx];
        __syncthreads();
        for (int r = 0; r < 32; r += 8)
            out[(size_t)(n0 + ty + r) * DMODEL + k0 + tx] = f2bf(tile[tx][ty + r]);
    }
}

// ---------------- FUSED QKV projection GEMM (R8) -----------------------------
// One kernel for Q,K,V sharing the A (xb) tile: 128m x 64n x 3z per block,
// 512 blocks = 2/CU exactly one round (vs 768 before). A staged ONCE per
// k-iter for 3 outputs (A-side L2 traffic /3); barriers total /1.5. V uses
// operand-swapped MFMA so its transposed store keeps l16->s contiguity.
// LDS 40KB: As[128][64] + Bs[3][64][64].
__global__ __launch_bounds__(256, 2) void qkv_gemm(
    const unsigned short* __restrict__ xb, const unsigned short* __restrict__ Wt,
    const float* __restrict__ bq, const float* __restrict__ bk, const float* __restrict__ bv,
    unsigned short* __restrict__ Qs, unsigned short* __restrict__ Ks,
    unsigned short* __restrict__ Vts) {
    const int b = blockIdx.x;
    const int mt = b & 31, nt = b >> 5;        // 32 m-tiles x 16 n-tiles
    const int m0 = mt * 128, n0 = nt * 64;

    __shared__ __align__(16) unsigned short As[128][64];
    __shared__ __align__(16) unsigned short Bs[3][64][64];

    const int tid = threadIdx.x;
    const int wave = tid >> 6, lane = tid & 63, l16 = lane & 15, quad = lane >> 4;
    const int wm = (wave >> 1) * 64, wn2 = (wave & 1) * 32;

    const int lr8 = lane >> 3;
    const int sc  = ((lane & 7) ^ lr8) * 8;    // swizzled source col (u16)

    f32x4 accQ[4][2], accK[4][2], accV[2][4];
#pragma unroll
    for (int mi = 0; mi < 4; mi++)
#pragma unroll
        for (int ni = 0; ni < 2; ni++) {
            accQ[mi][ni] = (f32x4){0.f, 0.f, 0.f, 0.f};
            accK[mi][ni] = (f32x4){0.f, 0.f, 0.f, 0.f};
            accV[ni][mi] = (f32x4){0.f, 0.f, 0.f, 0.f};
        }

    for (int j = 0; j < 16; ++j) {
        if (j) __syncthreads();                // readers of tile j-1 done
        const int k0 = j * 64;
#pragma unroll
        for (int c = 0; c < 4; c++) {          // A: 16 segs, 4/wave
            const int seg = wave * 4 + c;
            glds16(&xb[(size_t)(m0 + seg * 8 + lr8) * DMODEL + k0 + sc], &As[seg * 8][0]);
        }
#pragma unroll
        for (int c = 0; c < 6; c++) {          // B: 24 segs (3z x 8), 6/wave
            const int idx = wave * 6 + c;
            const int z = idx >> 3, seg = idx & 7;
            glds16(&Wt[(size_t)z * DMODEL * DMODEL + (size_t)(n0 + seg * 8 + lr8) * DMODEL + k0 + sc],
                   &Bs[z][seg * 8][0]);
        }
        __syncthreads();                       // stage landed (vmcnt drained)

#pragma unroll
        for (int ks = 0; ks < 2; ks++) {
            const int pc = ((ks * 4 + quad) ^ (l16 & 7)) * 8;
            bf16x8 a[4], bb[3][2];
#pragma unroll
            for (int mi = 0; mi < 4; mi++) a[mi] = ld8(&As[wm + mi * 16 + l16][pc]);
#pragma unroll
            for (int z = 0; z < 3; z++)
#pragma unroll
                for (int ni = 0; ni < 2; ni++) bb[z][ni] = ld8(&Bs[z][wn2 + ni * 16 + l16][pc]);
#pragma unroll
            for (int mi = 0; mi < 4; mi++)
#pragma unroll
                for (int ni = 0; ni < 2; ni++) {
                    accQ[mi][ni] = __builtin_amdgcn_mfma_f32_16x16x32_bf16(a[mi], bb[0][ni], accQ[mi][ni], 0, 0, 0);
                    accK[mi][ni] = __builtin_amdgcn_mfma_f32_16x16x32_bf16(a[mi], bb[1][ni], accK[mi][ni], 0, 0, 0);
                    accV[ni][mi] = __builtin_amdgcn_mfma_f32_16x16x32_bf16(bb[2][ni], a[mi], accV[ni][mi], 0, 0, 0);
                }
        }
    }

    const int hh = n0 >> 6;                    // head index (n0 multiple of 64)

    // ---- Q/K epilogue: col = l16 -> d; row = quad*4+r -> s ----
#pragma unroll
    for (int ni = 0; ni < 2; ni++) {
        const int n = n0 + wn2 + ni * 16 + l16;
        const float bqv = bq[n], bkv = bk[n];
        const int d = n & 63;
#pragma unroll
        for (int mi = 0; mi < 4; mi++)
#pragma unroll
            for (int r = 0; r < 4; r++) {
                const int m = m0 + wm + mi * 16 + quad * 4 + r;
                const int bi = m >> 11, s = m & 2047;
                Qs[((size_t)(bi * NHEADS + hh) * SLEN + s) * 64 + d] =
                    f2bf((accQ[mi][ni][r] + bqv) * QSCALE);
                Ks[((size_t)(bi * NHEADS + hh) * SLEN + s) * 64 + d] =
                    f2bf(accK[mi][ni][r] + bkv);
            }
    }
    // ---- V epilogue (swapped acc): col = l16 -> s; row = quad*4+r -> d ----
#pragma unroll
    for (int ni = 0; ni < 2; ni++)
#pragma unroll
        for (int r = 0; r < 4; r++) {
            const int n = n0 + wn2 + ni * 16 + quad * 4 + r;
            const float bvv = bv[n];
            const int d = n & 63;
#pragma unroll
            for (int mi = 0; mi < 4; mi++) {
                const int m = m0 + wm + mi * 16 + l16;
                const int bi = m >> 11, s = m & 2047;
                Vts[((size_t)((bi * NHEADS + hh) * 64 + d)) * SLEN + s] =
                    f2bf(accV[ni][mi][r] + bvv);
            }
        }
}

// ---------------- cooperative flash attention — R8 ---------------------------
// R6 structure (Er LDS ring — R1/R7 proved direct global Er reads are
// L2-contention-bound, ~100-106us both times) + E-carry: the band slides
// exactly 64 rows/iter, so iter j+1's accE[0] == iter j's accE[4] (same rows,
// same aq, same lane mapping). Carry the raw f32x4 -> -2 ds_read_b128 and
// -2 MFMA per wave-iter.
__global__ __launch_bounds__(256, 2) void attn_kernel(
    const unsigned short* __restrict__ Q,   // (BH,S,64), pre-scaled by QSCALE
    const unsigned short* __restrict__ K,   // (BH,S,64)
    const unsigned short* __restrict__ Vt,  // (BH,64,S)
    const unsigned short* __restrict__ Ep,  // (EPAD_ROWS,64)
    float* __restrict__ out) {              // (B,S,DMODEL)
    const int tid = threadIdx.x;
    const int wave = tid >> 6, lane = tid & 63, l16 = lane & 15, quad = lane >> 4;
    const int lr8 = lane >> 3;
    const int swz = ((lane & 7) ^ lr8) * 8;   // swizzled source chunk (u16)

    const int bh = blockIdx.x & 31;
    const int pg = blockIdx.x >> 5;            // 0..15

    __shared__ __align__(16) unsigned short Ksh[2][64 * 64];  // K tile  [t][d], dbuf
    __shared__ __align__(16) unsigned short Vsh[2][64 * 64];  // V^T tile[d][t], dbuf
    __shared__ __align__(16) unsigned short Esh[256 * 64];    // Er ring (4 panels)

    const unsigned short* Qb = Q + (size_t)bh * SLEN * 64;
    const unsigned short* Kb = K + (size_t)bh * SLEN * 64;
    const unsigned short* Vb = Vt + (size_t)bh * 64 * SLEN;
    const int ob = bh >> 4, oh = bh & 15;

    // hoisted loop-invariant lane math
    const int pc0 = (quad ^ (l16 & 7)) * 8;          // de-swizzle, k-chunk 0
    const int pc1 = ((4 + quad) ^ (l16 & 7)) * 8;    // de-swizzle, k-chunk 1
    // skew gather (swapped layout): receiver (quad,l16) output (nt,r) needs
    // band offset o = nt*16 + idx_v, idx_v = quad*4 + r + 15 - l16, served by
    // lane ((idx_v&15)>>2, l16) register (nt + (idx_v>=16))[idx_v&3].
    const int krot = (15 - l16) & 3;
    const bool c1 = (krot & 1) != 0, c2 = (krot & 2) != 0;
    int permE[4]; bool hiE[4];
#pragma unroll
    for (int r = 0; r < 4; r++) {
        const int idx = quad * 4 + r + 15 - l16;     // receiver-side idx_v: 0..30
        permE[r] = ((idx >> 2) & 3) * 16 + l16;      // sender lane to pull from
        const int c  = r + 15 - l16;                 // sender-side: 0..18
        const int qv = (quad - (c >> 2)) & 3;        // quad of receiver I serve
        hiE[r] = (qv * 4 + c) >= 16;                 // that receiver's idx_v>=16
    }

    int s0 = pg * 64;
    int ntp = pg + 1;

#pragma unroll 1
    for (int pass = 0; pass < 2; ++pass) {
        const int sw = s0 + 16 * wave;          // this wave's 16 q-rows
        const bf16x8 aq0 = ld8(Qb + (size_t)(sw + l16) * 64 + quad * 8);
        const bf16x8 aq1 = ld8(Qb + (size_t)(sw + l16) * 64 + 32 + quad * 8);

        f32x4 accO[4];                          // O^T: d = ntd*16+quad*4+r, q=l16
        float sacc[4];
#pragma unroll
        for (int nt = 0; nt < 4; nt++) accO[nt] = (f32x4){0.f, 0.f, 0.f, 0.f};
#pragma unroll
        for (int r = 0; r < 4; r++) sacc[r] = 0.f;

        const int p0row = SLEN - 64 - s0;       // Er panel base at t0=0 (mult of 64)

        // ---- prologue: K/V (t0=0) into buf0 + Er panels ----
#pragma unroll
        for (int c = 0; c < 2; c++) {
            const int seg = wave * 2 + c;
            glds16(&Kb[(size_t)(seg * 8 + lr8) * 64 + swz], &Ksh[0][seg * 8 * 64]);
            glds16(&Vb[(size_t)(seg * 8 + lr8) * SLEN + swz], &Vsh[0][seg * 8 * 64]);
        }
#pragma unroll
        for (int u = 0; u < 6; u++) {
            const int idx = wave * 6 + u;       // 24 segs = 3 panels (192 rows)
            const int grow = p0row + idx * 8;
            glds16(&Ep[(size_t)(grow + lr8) * 64 + swz], &Esh[(grow & 255) * 64]);
        }
        __syncthreads();

        f32x4 carryE = (f32x4){0.f, 0.f, 0.f, 0.f};  // accE[4] of prev iter

        for (int j = 0; j < ntp; ++j) {
            const int t0 = j * 64;
            const int cur = j & 1;

            // ---- prefetch next tile ----
            if (j + 1 < ntp) {
                const int t1 = t0 + 64, nb = cur ^ 1;
#pragma unroll
                for (int c = 0; c < 2; c++) {
                    const int seg = wave * 2 + c;
                    glds16(&Kb[(size_t)(t1 + seg * 8 + lr8) * 64 + swz], &Ksh[nb][seg * 8 * 64]);
                    glds16(&Vb[(size_t)(seg * 8 + lr8) * SLEN + t1 + swz], &Vsh[nb][seg * 8 * 64]);
                }
                const int er = p0row + t0 + 128;  // panel needed at iter j+1
#pragma unroll
                for (int c = 0; c < 2; c++) {
                    const int seg = wave * 2 + c;
                    glds16(&Ep[(size_t)(er + seg * 8 + lr8) * 64 + swz],
                           &Esh[((er + seg * 8) & 255) * 64]);
                }
            }

            // ---- QK^T swapped: S^T[t][q], t = nt*16+quad*4+r, q = l16 ----
            f32x4 accS[4];
#pragma unroll
            for (int nt = 0; nt < 4; nt++)
                accS[nt] = (f32x4){-EXPB, -EXPB, -EXPB, -EXPB};
#pragma unroll
            for (int nt = 0; nt < 4; nt++) {
                bf16x8 bk0 = ld8(&Ksh[cur][(nt * 16 + l16) * 64 + pc0]);
                bf16x8 bk1 = ld8(&Ksh[cur][(nt * 16 + l16) * 64 + pc1]);
                accS[nt] = __builtin_amdgcn_mfma_f32_16x16x32_bf16(bk0, aq0, accS[nt], 0, 0, 0);
                accS[nt] = __builtin_amdgcn_mfma_f32_16x16x32_bf16(bk1, aq1, accS[nt], 0, 0, 0);
            }

            // ---- rel band swapped: E^T[band row][q]; nt=0 carried from prev
            //      iter (band slides 64 rows: accE[0]_j+1 == accE[4]_j) ----
            const int rm0 = (SLEN - 16 - sw + t0) & 255;
            f32x4 accE[5];
            if (j == 0) {
                accE[0] = (f32x4){0.f, 0.f, 0.f, 0.f};
                const int rowm = (rm0 + l16) & 255;
                bf16x8 be0 = ld8(&Esh[rowm * 64 + pc0]);
                bf16x8 be1 = ld8(&Esh[rowm * 64 + pc1]);
                accE[0] = __builtin_amdgcn_mfma_f32_16x16x32_bf16(be0, aq0, accE[0], 0, 0, 0);
                accE[0] = __builtin_amdgcn_mfma_f32_16x16x32_bf16(be1, aq1, accE[0], 0, 0, 0);
            } else {
                accE[0] = carryE;
            }
#pragma unroll
            for (int nt = 1; nt < 5; nt++) {
                accE[nt] = (f32x4){0.f, 0.f, 0.f, 0.f};
                const int rowm = (rm0 + nt * 16 + l16) & 255;
                bf16x8 be0 = ld8(&Esh[rowm * 64 + pc0]);
                bf16x8 be1 = ld8(&Esh[rowm * 64 + pc1]);
                accE[nt] = __builtin_amdgcn_mfma_f32_16x16x32_bf16(be0, aq0, accE[nt], 0, 0, 0);
                accE[nt] = __builtin_amdgcn_mfma_f32_16x16x32_bf16(be1, aq1, accE[nt], 0, 0, 0);
            }
            carryE = accE[4];

            // ---- per-lane register rotation of accE groups by krot ----
            f32x4 rotE[5];
#pragma unroll
            for (int g = 0; g < 5; g++) {
                f32x4 A = accE[g], t, rt;
#pragma unroll
                for (int r = 0; r < 4; r++) t[r] = c1 ? A[(r + 1) & 3] : A[r];
#pragma unroll
                for (int r = 0; r < 4; r++) rt[r] = c2 ? t[(r + 2) & 3] : t[r];
                rotE[g] = rt;
            }

            // ---- skew gather + exp2 (mask only on diagonal tile) ----
            float pe[4][4];
            auto scoreblk = [&](bool masked) {
#pragma unroll
                for (int nt = 0; nt < 4; nt++) {
#pragma unroll
                    for (int r = 0; r < 4; r++) {
                        float send = hiE[r] ? rotE[nt + 1][r] : rotE[nt][r];
                        float rel = __shfl(send, permE[r]);
                        float p = exp2_hw(accS[nt][r] + rel);
                        if (masked)
                            p = (t0 + nt * 16 + quad * 4 + r <= sw + l16) ? p : 0.0f;
                        sacc[r] += p;
                        pe[nt][r] = p;
                    }
                }
            };
            if (t0 + 63 <= sw) scoreblk(false);   // fully-unmasked tile
            else               scoreblk(true);    // diagonal tile

            // ---- P^T -> bf16 B-frags, in-register (cvt_pk + permlane) ----
            unsigned int w[4][2];
#pragma unroll
            for (int nt = 0; nt < 4; nt++) {
                w[nt][0] = cvtpk_bf16(pe[nt][0], pe[nt][1]);
                w[nt][1] = cvtpk_bf16(pe[nt][2], pe[nt][3]);
            }
            bf16x8 pf[2];
#pragma unroll
            for (int c = 0; c < 2; c++) {
                unsigned int a0 = w[2 * c][0], b0 = w[2 * c + 1][0];
                unsigned int a1 = w[2 * c][1], b1 = w[2 * c + 1][1];
                asm volatile("v_permlane32_swap_b32 %0, %1" : "+v"(a0), "+v"(b0));
                asm volatile("v_permlane16_swap_b32 %0, %1" : "+v"(a0), "+v"(b0));
                asm volatile("v_permlane32_swap_b32 %0, %1" : "+v"(a1), "+v"(b1));
                asm volatile("v_permlane16_swap_b32 %0, %1" : "+v"(a1), "+v"(b1));
                union { uint4 u; bf16x8 b; } t;
                t.u = (uint4){a0, a1, b0, b1};
                pf[c] = t.b;
            }

            // ---- PV swapped: O^T += V^T x P^T ----
#pragma unroll
            for (int ntd = 0; ntd < 4; ntd++) {
                bf16x8 bv0 = ld8(&Vsh[cur][(ntd * 16 + l16) * 64 + pc0]);
                bf16x8 bv1 = ld8(&Vsh[cur][(ntd * 16 + l16) * 64 + pc1]);
                accO[ntd] = __builtin_amdgcn_mfma_f32_16x16x32_bf16(bv0, pf[0], accO[ntd], 0, 0, 0);
                accO[ntd] = __builtin_amdgcn_mfma_f32_16x16x32_bf16(bv1, pf[1], accO[ntd], 0, 0, 0);
            }

            __syncthreads();   // staged j+1 landed; compute j done before overwrite
        }

        // ---- pass epilogue: cross-quad denom reduce + normalize + store ----
        float s4 = (sacc[0] + sacc[1]) + (sacc[2] + sacc[3]);
        s4 += __shfl_xor(s4, 16);
        s4 += __shfl_xor(s4, 32);
        const float inv = 1.f / s4;
        const int srow = sw + l16;
        float* orow = out + ((size_t)(ob * SLEN + srow)) * DMODEL + oh * 64 + quad * 4;
#pragma unroll
        for (int ntd = 0; ntd < 4; ntd++) {
            float4 st = {accO[ntd][0] * inv, accO[ntd][1] * inv,
                         accO[ntd][2] * inv, accO[ntd][3] * inv};
            *(float4*)(orow + ntd * 16) = st;
        }

        // switch to pass B: q-tile 31-pg
        s0 = (31 - pg) * 64;
        ntp = 32 - pg;
    }
}

// ---------------- host launcher ----------------
extern "C" void kernel_launch(void* const* d_in, const int* in_sizes, int n_in,
                              void* d_out, int out_size, void* d_ws, size_t ws_size,
                              hipStream_t stream) {
    const float* x  = (const float*)d_in[0];
    const float* Wq = (const float*)d_in[1];
    const float* bq = (const float*)d_in[2];
    const float* Wk = (const float*)d_in[3];
    const float* bk = (const float*)d_in[4];
    const float* Wv = (const float*)d_in[5];
    const float* bv = (const float*)d_in[6];
    const float* Er = (const float*)d_in[7];
    float* out = (float*)d_out;

    // workspace carve (~38.4 MB total)
    char* p = (char*)d_ws;
    unsigned short* xb  = (unsigned short*)p; p += (size_t)4096 * 1024 * 2;
    unsigned short* Wt  = (unsigned short*)p; p += (size_t)3 * 1024 * 1024 * 2;
    unsigned short* Qs  = (unsigned short*)p; p += (size_t)32 * 2048 * 64 * 2;
    unsigned short* Ks  = (unsigned short*)p; p += (size_t)32 * 2048 * 64 * 2;
    unsigned short* Vts = (unsigned short*)p; p += (size_t)32 * 2048 * 64 * 2;
    unsigned short* Ep  = (unsigned short*)p; p += (size_t)EPAD_ROWS * 64 * 2;

    hipLaunchKernelGGL(prep_kernel, dim3(7776), dim3(256), 0, stream,
                       x, Er, Wq, Wk, Wv, xb, Ep, Wt);
    hipLaunchKernelGGL(qkv_gemm, dim3(512), dim3(256), 0, stream,
                       xb, Wt, bq, bk, bv, Qs, Ks, Vts);
    hipLaunchKernelGGL(attn_kernel, dim3(512), dim3(256), 0, stream, Qs, Ks, Vts, Ep, out);
}

// Round 9
// 168.828 us; speedup vs baseline: 1.2405x; 1.0134x over previous
//
#include <hip/hip_runtime.h>
#include <hip/hip_bf16.h>

#define SLEN   2048
#define DMODEL 1024
#define NHEADS 16
#define DHEAD  64
#define NBATCH 2
#define EPAD_ROWS 2432   // SLEN + 384 zero rows so rel-band/ring never reads OOB

// Q pre-scale folds softmax 1/8 AND log2(e) so scores are in exp2 domain
#define QSCALE 0.18033688011112042f     // 0.125 * log2(e)
#define EXPB   23.083120654223414f      // 16 * log2(e)

typedef __bf16 bf16x8 __attribute__((ext_vector_type(8)));
typedef float  f32x4  __attribute__((ext_vector_type(4)));

__device__ __forceinline__ unsigned short f2bf(float f) {
    unsigned int u = __builtin_bit_cast(unsigned int, f);
    return (unsigned short)((u + 0x7fffu + ((u >> 16) & 1u)) >> 16);  // RNE
}

// bare v_exp_f32 (2^x); args in [-60, 20], flush-to-zero fine
__device__ __forceinline__ float exp2_hw(float x) {
    float r;
    asm("v_exp_f32 %0, %1" : "=v"(r) : "v"(x));
    return r;
}

// pack two f32 -> (bf16 lo, bf16 hi), RNE
__device__ __forceinline__ unsigned int cvtpk_bf16(float lo, float hi) {
    unsigned int d;
    asm("v_cvt_pk_bf16_f32 %0, %1, %2" : "=v"(d) : "v"(lo), "v"(hi));
    return d;
}

__device__ __forceinline__ bf16x8 ld8(const unsigned short* p) {
    union { uint4 u; bf16x8 b; } t;
    t.u = *(const uint4*)p;
    return t.b;
}

// async global->LDS, 16B per lane; lds base must be wave-uniform
__device__ __forceinline__ void glds16(const unsigned short* g, unsigned short* l) {
    __builtin_amdgcn_global_load_lds(
        (const __attribute__((address_space(1))) unsigned int*)g,
        (__attribute__((address_space(3))) unsigned int*)l, 16, 0, 0);
}

// ---------------- merged prep kernel ----------------
__global__ __launch_bounds__(256) void prep_kernel(
    const float* __restrict__ x, const float* __restrict__ Er,
    const float* __restrict__ Wq, const float* __restrict__ Wk,
    const float* __restrict__ Wv,
    unsigned short* __restrict__ xb, unsigned short* __restrict__ Ep,
    unsigned short* __restrict__ Wt) {
    const int bi = blockIdx.x, tid = threadIdx.x;
    if (bi < 4096) {
        int i = (bi * 256 + tid) * 4;
        float4 v = *(const float4*)(x + i);
        ushort4 o;
        o.x = f2bf(v.x); o.y = f2bf(v.y); o.z = f2bf(v.z); o.w = f2bf(v.w);
        *(ushort4*)(xb + i) = o;
    } else if (bi < 4704) {
        int i = (bi - 4096) * 256 + tid;        // 2432*64 elements
        int row = i >> 6;
        unsigned short v = 0;
        if (row < SLEN) v = f2bf(Er[i]);
        Ep[i] = v;
    } else {
        __shared__ float tile[32][33];
        const int b3 = bi - 4704;               // 0..3071
        const int z = b3 >> 10, rem = b3 & 1023;
        const int n0 = (rem & 31) * 32, k0 = (rem >> 5) * 32;
        const float* W = (z == 0) ? Wq : (z == 1 ? Wk : Wv);
        unsigned short* out = Wt + (size_t)z * DMODEL * DMODEL;
        const int tx = tid & 31, ty = tid >> 5;  // (32,8)
        for (int r = 0; r < 32; r += 8)
            tile[ty + r][tx] = W[(size_t)(k0 + ty + r) * DMODEL + n0 + tx];
        __syncthreads();
        for (int r = 0; r < 32; r += 8)
            out[(size_t)(n0 + ty + r) * DMODEL + k0 + tx] = f2bf(tile[tx][ty + r]);
    }
}

// ---------------- FUSED QKV projection GEMM (R8, unchanged) ------------------
__global__ __launch_bounds__(256, 2) void qkv_gemm(
    const unsigned short* __restrict__ xb, const unsigned short* __restrict__ Wt,
    const float* __restrict__ bq, const float* __restrict__ bk, const float* __restrict__ bv,
    unsigned short* __restrict__ Qs, unsigned short* __restrict__ Ks,
    unsigned short* __restrict__ Vts) {
    const int b = blockIdx.x;
    const int mt = b & 31, nt = b >> 5;        // 32 m-tiles x 16 n-tiles
    const int m0 = mt * 128, n0 = nt * 64;

    __shared__ __align__(16) unsigned short As[128][64];
    __shared__ __align__(16) unsigned short Bs[3][64][64];

    const int tid = threadIdx.x;
    const int wave = tid >> 6, lane = tid & 63, l16 = lane & 15, quad = lane >> 4;
    const int wm = (wave >> 1) * 64, wn2 = (wave & 1) * 32;

    const int lr8 = lane >> 3;
    const int sc  = ((lane & 7) ^ lr8) * 8;    // swizzled source col (u16)

    f32x4 accQ[4][2], accK[4][2], accV[2][4];
#pragma unroll
    for (int mi = 0; mi < 4; mi++)
#pragma unroll
        for (int ni = 0; ni < 2; ni++) {
            accQ[mi][ni] = (f32x4){0.f, 0.f, 0.f, 0.f};
            accK[mi][ni] = (f32x4){0.f, 0.f, 0.f, 0.f};
            accV[ni][mi] = (f32x4){0.f, 0.f, 0.f, 0.f};
        }

    for (int j = 0; j < 16; ++j) {
        if (j) __syncthreads();                // readers of tile j-1 done
        const int k0 = j * 64;
#pragma unroll
        for (int c = 0; c < 4; c++) {          // A: 16 segs, 4/wave
            const int seg = wave * 4 + c;
            glds16(&xb[(size_t)(m0 + seg * 8 + lr8) * DMODEL + k0 + sc], &As[seg * 8][0]);
        }
#pragma unroll
        for (int c = 0; c < 6; c++) {          // B: 24 segs (3z x 8), 6/wave
            const int idx = wave * 6 + c;
            const int z = idx >> 3, seg = idx & 7;
            glds16(&Wt[(size_t)z * DMODEL * DMODEL + (size_t)(n0 + seg * 8 + lr8) * DMODEL + k0 + sc],
                   &Bs[z][seg * 8][0]);
        }
        __syncthreads();                       // stage landed (vmcnt drained)

#pragma unroll
        for (int ks = 0; ks < 2; ks++) {
            const int pc = ((ks * 4 + quad) ^ (l16 & 7)) * 8;
            bf16x8 a[4], bb[3][2];
#pragma unroll
            for (int mi = 0; mi < 4; mi++) a[mi] = ld8(&As[wm + mi * 16 + l16][pc]);
#pragma unroll
            for (int z = 0; z < 3; z++)
#pragma unroll
                for (int ni = 0; ni < 2; ni++) bb[z][ni] = ld8(&Bs[z][wn2 + ni * 16 + l16][pc]);
#pragma unroll
            for (int mi = 0; mi < 4; mi++)
#pragma unroll
                for (int ni = 0; ni < 2; ni++) {
                    accQ[mi][ni] = __builtin_amdgcn_mfma_f32_16x16x32_bf16(a[mi], bb[0][ni], accQ[mi][ni], 0, 0, 0);
                    accK[mi][ni] = __builtin_amdgcn_mfma_f32_16x16x32_bf16(a[mi], bb[1][ni], accK[mi][ni], 0, 0, 0);
                    accV[ni][mi] = __builtin_amdgcn_mfma_f32_16x16x32_bf16(bb[2][ni], a[mi], accV[ni][mi], 0, 0, 0);
                }
        }
    }

    const int hh = n0 >> 6;                    // head index (n0 multiple of 64)

    // ---- Q/K epilogue: col = l16 -> d; row = quad*4+r -> s ----
#pragma unroll
    for (int ni = 0; ni < 2; ni++) {
        const int n = n0 + wn2 + ni * 16 + l16;
        const float bqv = bq[n], bkv = bk[n];
        const int d = n & 63;
#pragma unroll
        for (int mi = 0; mi < 4; mi++)
#pragma unroll
            for (int r = 0; r < 4; r++) {
                const int m = m0 + wm + mi * 16 + quad * 4 + r;
                const int bi = m >> 11, s = m & 2047;
                Qs[((size_t)(bi * NHEADS + hh) * SLEN + s) * 64 + d] =
                    f2bf((accQ[mi][ni][r] + bqv) * QSCALE);
                Ks[((size_t)(bi * NHEADS + hh) * SLEN + s) * 64 + d] =
                    f2bf(accK[mi][ni][r] + bkv);
            }
    }
    // ---- V epilogue (swapped acc): col = l16 -> s; row = quad*4+r -> d ----
#pragma unroll
    for (int ni = 0; ni < 2; ni++)
#pragma unroll
        for (int r = 0; r < 4; r++) {
            const int n = n0 + wn2 + ni * 16 + quad * 4 + r;
            const float bvv = bv[n];
            const int d = n & 63;
#pragma unroll
            for (int mi = 0; mi < 4; mi++) {
                const int m = m0 + wm + mi * 16 + l16;
                const int bi = m >> 11, s = m & 2047;
                Vts[((size_t)((bi * NHEADS + hh) * 64 + d)) * SLEN + s] =
                    f2bf(accV[ni][mi][r] + bvv);
            }
        }
}

// ---------------- cooperative flash attention — R9 ---------------------------
// Occupancy unlock: the 512-block fold capped residency at 2 blocks/CU (grid
// == capacity), and 64KB LDS capped capacity at 2 anyway. Now: 1024 blocks
// (one q-tile each, long blocks dispatched first), LDS 48KB (Esh 192-row
// exact 3-panel ring + SINGLE-buffered K), 3 blocks/CU, 12 waves. Iteration
// restructured for single-K: QK^T -> barrier1 (zero outstanding DMA -> its
// vmcnt(0) is free) -> all stages (K/V/E) -> E/softmax/PV (~400cyc DMA cover)
// -> barrier2. Ring invariant: reads span rel [t0,t0+128), prefetch
// [t0+128,t0+192), disjoint mod 192.
__global__ __launch_bounds__(256, 3) void attn_kernel(
    const unsigned short* __restrict__ Q,   // (BH,S,64), pre-scaled by QSCALE
    const unsigned short* __restrict__ K,   // (BH,S,64)
    const unsigned short* __restrict__ Vt,  // (BH,64,S)
    const unsigned short* __restrict__ Ep,  // (EPAD_ROWS,64)
    float* __restrict__ out) {              // (B,S,DMODEL)
    const int tid = threadIdx.x;
    const int wave = tid >> 6, lane = tid & 63, l16 = lane & 15, quad = lane >> 4;
    const int lr8 = lane >> 3;
    const int swz = ((lane & 7) ^ lr8) * 8;   // swizzled source chunk (u16)

    const int bh = blockIdx.x & 31;
    const int qt = 31 - (blockIdx.x >> 5);     // descending trips: long first
    const int s0 = qt * 64;
    const int ntp = qt + 1;

    __shared__ __align__(16) unsigned short Ksh[64 * 64];     // K tile, SINGLE buf
    __shared__ __align__(16) unsigned short Vsh[2][64 * 64];  // V^T tile, dbuf
    __shared__ __align__(16) unsigned short Esh[192 * 64];    // Er ring, 3 panels

    const unsigned short* Qb = Q + (size_t)bh * SLEN * 64;
    const unsigned short* Kb = K + (size_t)bh * SLEN * 64;
    const unsigned short* Vb = Vt + (size_t)bh * 64 * SLEN;
    const int ob = bh >> 4, oh = bh & 15;

    // hoisted loop-invariant lane math
    const int pc0 = (quad ^ (l16 & 7)) * 8;          // de-swizzle, k-chunk 0
    const int pc1 = ((4 + quad) ^ (l16 & 7)) * 8;    // de-swizzle, k-chunk 1
    // skew gather: receiver (quad,l16) output (nt,r) needs band offset
    // nt*16 + idx_v, idx_v = quad*4+r+15-l16; sender-side group select uses
    // the RECEIVER's idx_v reconstructed from sender coords (R5 fix).
    const int krot = (15 - l16) & 3;
    const bool c1 = (krot & 1) != 0, c2 = (krot & 2) != 0;
    int permE[4]; bool hiE[4];
#pragma unroll
    for (int r = 0; r < 4; r++) {
        const int idx = quad * 4 + r + 15 - l16;     // receiver-side idx_v: 0..30
        permE[r] = ((idx >> 2) & 3) * 16 + l16;      // sender lane to pull from
        const int c  = r + 15 - l16;                 // sender-side: 0..18
        const int qv = (quad - (c >> 2)) & 3;        // quad of receiver I serve
        hiE[r] = (qv * 4 + c) >= 16;                 // that receiver's idx_v>=16
    }

    const int sw = s0 + 16 * wave;          // this wave's 16 q-rows
    const bf16x8 aq0 = ld8(Qb + (size_t)(sw + l16) * 64 + quad * 8);
    const bf16x8 aq1 = ld8(Qb + (size_t)(sw + l16) * 64 + 32 + quad * 8);

    f32x4 accO[4];                          // O^T: d = ntd*16+quad*4+r, q=l16
    float sacc[4];
#pragma unroll
    for (int nt = 0; nt < 4; nt++) accO[nt] = (f32x4){0.f, 0.f, 0.f, 0.f};
#pragma unroll
    for (int r = 0; r < 4; r++) sacc[r] = 0.f;

    const int p0row = SLEN - 64 - s0;       // Er ring origin (rel row 0)

    // ---- prologue: K(0), V(0)->buf0, Er rel rows [0,128) ----
#pragma unroll
    for (int c = 0; c < 2; c++) {
        const int seg = wave * 2 + c;
        glds16(&Kb[(size_t)(seg * 8 + lr8) * 64 + swz], &Ksh[seg * 8 * 64]);
        glds16(&Vb[(size_t)(seg * 8 + lr8) * SLEN + swz], &Vsh[0][seg * 8 * 64]);
    }
#pragma unroll
    for (int u = 0; u < 4; u++) {
        const int idx = wave * 4 + u;       // 16 segs = rel rows [0,128)
        glds16(&Ep[(size_t)(p0row + idx * 8 + lr8) * 64 + swz], &Esh[idx * 8 * 64]);
    }
    __syncthreads();

    f32x4 carryE = (f32x4){0.f, 0.f, 0.f, 0.f};  // accE[4] of prev iter
    int rb = 48 - 16 * wave;                // ring base (rel) for this wave
    int ed = 128;                           // ring dest base for prefetch

    for (int j = 0; j < ntp; ++j) {
        const int t0 = j * 64;
        const int cur = j & 1;

        // ---- 1) QK^T from single-buffered Ksh ----
        f32x4 accS[4];
#pragma unroll
        for (int nt = 0; nt < 4; nt++)
            accS[nt] = (f32x4){-EXPB, -EXPB, -EXPB, -EXPB};
#pragma unroll
        for (int nt = 0; nt < 4; nt++) {
            bf16x8 bk0 = ld8(&Ksh[(nt * 16 + l16) * 64 + pc0]);
            bf16x8 bk1 = ld8(&Ksh[(nt * 16 + l16) * 64 + pc1]);
            accS[nt] = __builtin_amdgcn_mfma_f32_16x16x32_bf16(bk0, aq0, accS[nt], 0, 0, 0);
            accS[nt] = __builtin_amdgcn_mfma_f32_16x16x32_bf16(bk1, aq1, accS[nt], 0, 0, 0);
        }

        __syncthreads();   // barrier1: all waves done reading Ksh(j); no DMA outstanding

        // ---- 2) stage K(j+1)/V(j+1)/E(t0+128) — drains at barrier2 with
        //         E-MFMA+softmax+PV as cover ----
        if (j + 1 < ntp) {
            const int t1 = t0 + 64, nb = cur ^ 1;
#pragma unroll
            for (int c = 0; c < 2; c++) {
                const int seg = wave * 2 + c;
                glds16(&Kb[(size_t)(t1 + seg * 8 + lr8) * 64 + swz], &Ksh[seg * 8 * 64]);
                glds16(&Vb[(size_t)(seg * 8 + lr8) * SLEN + t1 + swz], &Vsh[nb][seg * 8 * 64]);
            }
            const int er = p0row + t0 + 128;  // absolute Er rows for iter j+1
#pragma unroll
            for (int c = 0; c < 2; c++) {
                const int seg = wave * 2 + c;
                glds16(&Ep[(size_t)(er + seg * 8 + lr8) * 64 + swz],
                       &Esh[(ed + seg * 8) * 64]);
            }
        }

        // ---- 3) rel band from ring; nt=0 carried (band slides 64/iter) ----
        const int base = rb + l16;          // <= 191
        f32x4 accE[5];
        if (j == 0) {
            accE[0] = (f32x4){0.f, 0.f, 0.f, 0.f};
            bf16x8 be0 = ld8(&Esh[base * 64 + pc0]);   // base <= 63 at j=0
            bf16x8 be1 = ld8(&Esh[base * 64 + pc1]);
            accE[0] = __builtin_amdgcn_mfma_f32_16x16x32_bf16(be0, aq0, accE[0], 0, 0, 0);
            accE[0] = __builtin_amdgcn_mfma_f32_16x16x32_bf16(be1, aq1, accE[0], 0, 0, 0);
        } else {
            accE[0] = carryE;
        }
#pragma unroll
        for (int nt = 1; nt < 5; nt++) {
            int row = base + nt * 16;
            if (row >= 192) row -= 192;     // single wrap (base<=191, +64 max)
            accE[nt] = (f32x4){0.f, 0.f, 0.f, 0.f};
            bf16x8 be0 = ld8(&Esh[row * 64 + pc0]);
            bf16x8 be1 = ld8(&Esh[row * 64 + pc1]);
            accE[nt] = __builtin_amdgcn_mfma_f32_16x16x32_bf16(be0, aq0, accE[nt], 0, 0, 0);
            accE[nt] = __builtin_amdgcn_mfma_f32_16x16x32_bf16(be1, aq1, accE[nt], 0, 0, 0);
        }
        carryE = accE[4];
        rb += 64; if (rb >= 192) rb -= 192;
        ed += 64; if (ed >= 192) ed -= 192;

        // ---- per-lane register rotation of accE groups by krot ----
        f32x4 rotE[5];
#pragma unroll
        for (int g = 0; g < 5; g++) {
            f32x4 A = accE[g], t, rt;
#pragma unroll
            for (int r = 0; r < 4; r++) t[r] = c1 ? A[(r + 1) & 3] : A[r];
#pragma unroll
            for (int r = 0; r < 4; r++) rt[r] = c2 ? t[(r + 2) & 3] : t[r];
            rotE[g] = rt;
        }

        // ---- skew gather + exp2 (mask only on diagonal tile) ----
        float pe[4][4];
        auto scoreblk = [&](bool masked) {
#pragma unroll
            for (int nt = 0; nt < 4; nt++) {
#pragma unroll
                for (int r = 0; r < 4; r++) {
                    float send = hiE[r] ? rotE[nt + 1][r] : rotE[nt][r];
                    float rel = __shfl(send, permE[r]);
                    float p = exp2_hw(accS[nt][r] + rel);
                    if (masked)
                        p = (t0 + nt * 16 + quad * 4 + r <= sw + l16) ? p : 0.0f;
                    sacc[r] += p;
                    pe[nt][r] = p;
                }
            }
        };
        if (t0 + 63 <= sw) scoreblk(false);   // fully-unmasked tile
        else               scoreblk(true);    // diagonal tile

        // ---- P^T -> bf16 B-frags, in-register (cvt_pk + permlane) ----
        unsigned int w[4][2];
#pragma unroll
        for (int nt = 0; nt < 4; nt++) {
            w[nt][0] = cvtpk_bf16(pe[nt][0], pe[nt][1]);
            w[nt][1] = cvtpk_bf16(pe[nt][2], pe[nt][3]);
        }
        bf16x8 pf[2];
#pragma unroll
        for (int c = 0; c < 2; c++) {
            unsigned int a0 = w[2 * c][0], b0 = w[2 * c + 1][0];
            unsigned int a1 = w[2 * c][1], b1 = w[2 * c + 1][1];
            asm volatile("v_permlane32_swap_b32 %0, %1" : "+v"(a0), "+v"(b0));
            asm volatile("v_permlane16_swap_b32 %0, %1" : "+v"(a0), "+v"(b0));
            asm volatile("v_permlane32_swap_b32 %0, %1" : "+v"(a1), "+v"(b1));
            asm volatile("v_permlane16_swap_b32 %0, %1" : "+v"(a1), "+v"(b1));
            union { uint4 u; bf16x8 b; } t;
            t.u = (uint4){a0, a1, b0, b1};
            pf[c] = t.b;
        }

        // ---- PV swapped: O^T += V^T x P^T ----
#pragma unroll
        for (int ntd = 0; ntd < 4; ntd++) {
            bf16x8 bv0 = ld8(&Vsh[cur][(ntd * 16 + l16) * 64 + pc0]);
            bf16x8 bv1 = ld8(&Vsh[cur][(ntd * 16 + l16) * 64 + pc1]);
            accO[ntd] = __builtin_amdgcn_mfma_f32_16x16x32_bf16(bv0, pf[0], accO[ntd], 0, 0, 0);
            accO[ntd] = __builtin_amdgcn_mfma_f32_16x16x32_bf16(bv1, pf[1], accO[ntd], 0, 0, 0);
        }

        __syncthreads();   // barrier2: stages landed; K(j) fully consumed
    }

    // ---- epilogue: cross-quad denom reduce + normalize + store ----
    float s4 = (sacc[0] + sacc[1]) + (sacc[2] + sacc[3]);
    s4 += __shfl_xor(s4, 16);
    s4 += __shfl_xor(s4, 32);
    const float inv = 1.f / s4;
    const int srow = sw + l16;
    float* orow = out + ((size_t)(ob * SLEN + srow)) * DMODEL + oh * 64 + quad * 4;
#pragma unroll
    for (int ntd = 0; ntd < 4; ntd++) {
        float4 st = {accO[ntd][0] * inv, accO[ntd][1] * inv,
                     accO[ntd][2] * inv, accO[ntd][3] * inv};
        *(float4*)(orow + ntd * 16) = st;
    }
}

// ---------------- host launcher ----------------
extern "C" void kernel_launch(void* const* d_in, const int* in_sizes, int n_in,
                              void* d_out, int out_size, void* d_ws, size_t ws_size,
                              hipStream_t stream) {
    const float* x  = (const float*)d_in[0];
    const float* Wq = (const float*)d_in[1];
    const float* bq = (const float*)d_in[2];
    const float* Wk = (const float*)d_in[3];
    const float* bk = (const float*)d_in[4];
    const float* Wv = (const float*)d_in[5];
    const float* bv = (const float*)d_in[6];
    const float* Er = (const float*)d_in[7];
    float* out = (float*)d_out;

    // workspace carve (~38.4 MB total)
    char* p = (char*)d_ws;
    unsigned short* xb  = (unsigned short*)p; p += (size_t)4096 * 1024 * 2;
    unsigned short* Wt  = (unsigned short*)p; p += (size_t)3 * 1024 * 1024 * 2;
    unsigned short* Qs  = (unsigned short*)p; p += (size_t)32 * 2048 * 64 * 2;
    unsigned short* Ks  = (unsigned short*)p; p += (size_t)32 * 2048 * 64 * 2;
    unsigned short* Vts = (unsigned short*)p; p += (size_t)32 * 2048 * 64 * 2;
    unsigned short* Ep  = (unsigned short*)p; p += (size_t)EPAD_ROWS * 64 * 2;

    hipLaunchKernelGGL(prep_kernel, dim3(7776), dim3(256), 0, stream,
                       x, Er, Wq, Wk, Wv, xb, Ep, Wt);
    hipLaunchKernelGGL(qkv_gemm, dim3(512), dim3(256), 0, stream,
                       xb, Wt, bq, bk, bv, Qs, Ks, Vts);
    hipLaunchKernelGGL(attn_kernel, dim3(1024), dim3(256), 0, stream, Qs, Ks, Vts, Ep, out);
}